// Round 1
// baseline (113.936 us; speedup 1.0000x reference)
//
#include <hip/hip_runtime.h>
#include <math.h>

// KDE: out[i] = mean_n coef * exp(-||test_i - train_n||^2 / (2*var)), var = 0.04^2
// B*T = 1024 test points, N = 4096 train points, D = 64, all fp32.
//
// Design: grid 512 = 128 test-tiles(8 tests) x 4 train-quarters(1024 rows).
// Block = 256 thr = 4 waves; wave w owns tests tile*8 + 2w, +1 (TP=2 in VGPRs).
// Lanes stride train rows, float4 row reads (L1/L2 resident), diff-form fp32,
// exp2f -> v_exp_f32, wave shuffle reduce, atomicAdd per (wave,test).

#define D            64
#define N_TRAIN      4096
#define QUARTERS     4
#define TRAINS_PER_Q (N_TRAIN / QUARTERS)   // 1024
#define VISITS       (TRAINS_PER_Q / 64)    // 16

// exp(-sqd/(2*var)) = exp2(sqd * EXP2_SCALE); 2*var = 0.0032
#define EXP2_SCALE   (-450.84220027780106f)   // -log2(e)/0.0032
#define COEF         (9.973557010035818f)     // 1/sqrt(2*pi*var)

__global__ void kde_zero(float* __restrict__ out) {
    out[blockIdx.x * 256 + threadIdx.x] = 0.0f;
}

__global__ __launch_bounds__(256, 2) void kde_main(
    const float* __restrict__ test,
    const float* __restrict__ train,
    float* __restrict__ out)
{
    const int tid  = threadIdx.x;
    const int lane = tid & 63;
    const int wave = tid >> 6;
    const int q    = blockIdx.x & 3;      // train quarter
    const int tt   = blockIdx.x >> 2;     // test tile (8 tests)
    const int t0   = tt * 8 + wave * 2;   // this wave's two tests

    // Load both test vectors into registers (wave-uniform addresses).
    float x0[D], x1[D];
    {
        const float4* p0 = (const float4*)(test + (size_t)t0 * D);
        const float4* p1 = (const float4*)(test + (size_t)(t0 + 1) * D);
        #pragma unroll
        for (int d4 = 0; d4 < D / 4; ++d4) {
            float4 a = p0[d4];
            float4 b = p1[d4];
            x0[4*d4+0] = a.x; x0[4*d4+1] = a.y; x0[4*d4+2] = a.z; x0[4*d4+3] = a.w;
            x1[4*d4+0] = b.x; x1[4*d4+1] = b.y; x1[4*d4+2] = b.z; x1[4*d4+3] = b.w;
        }
    }

    float sum0 = 0.0f, sum1 = 0.0f;
    const int nbase = q * TRAINS_PER_Q + lane;

    for (int i = 0; i < VISITS; ++i) {
        const float4* trow = (const float4*)(train + (size_t)(nbase + i * 64) * D);
        float a0 = 0.0f, a1 = 0.0f;
        #pragma unroll
        for (int d4 = 0; d4 < D / 4; ++d4) {
            float4 t = trow[d4];
            float d;
            d = t.x - x0[4*d4+0]; a0 = fmaf(d, d, a0);
            d = t.y - x0[4*d4+1]; a0 = fmaf(d, d, a0);
            d = t.z - x0[4*d4+2]; a0 = fmaf(d, d, a0);
            d = t.w - x0[4*d4+3]; a0 = fmaf(d, d, a0);
            d = t.x - x1[4*d4+0]; a1 = fmaf(d, d, a1);
            d = t.y - x1[4*d4+1]; a1 = fmaf(d, d, a1);
            d = t.z - x1[4*d4+2]; a1 = fmaf(d, d, a1);
            d = t.w - x1[4*d4+3]; a1 = fmaf(d, d, a1);
        }
        sum0 += exp2f(a0 * EXP2_SCALE);
        sum1 += exp2f(a1 * EXP2_SCALE);
        __syncthreads();   // keep the block's waves on the same L1 window
    }

    // Wave-level reduction (64 lanes).
    #pragma unroll
    for (int off = 32; off > 0; off >>= 1) {
        sum0 += __shfl_down(sum0, off, 64);
        sum1 += __shfl_down(sum1, off, 64);
    }
    if (lane == 0) {
        const float scale = COEF / (float)N_TRAIN;
        atomicAdd(&out[t0],     sum0 * scale);
        atomicAdd(&out[t0 + 1], sum1 * scale);
    }
}

extern "C" void kernel_launch(void* const* d_in, const int* in_sizes, int n_in,
                              void* d_out, int out_size, void* d_ws, size_t ws_size,
                              hipStream_t stream) {
    const float* test  = (const float*)d_in[0];   // [4,256,64]
    const float* train = (const float*)d_in[1];   // [4096,64]
    float* out = (float*)d_out;                   // [4,256] -> 1024 floats

    kde_zero<<<dim3(out_size / 256), dim3(256), 0, stream>>>(out);
    kde_main<<<dim3(512), dim3(256), 0, stream>>>(test, train, out);
}

// Round 2
// 96.243 us; speedup vs baseline: 1.1838x; 1.1838x over previous
//
#include <hip/hip_runtime.h>
#include <math.h>

// KDE via dot-product form: sqd = ||x||^2 + ||t||^2 - 2 x.t
// exp(-sqd/(2*var)) = exp2(EXP2_SCALE * sqd), var = 0.04^2, 2var = 0.0032
//
// prep kernel: zero out[1024]; ws[i] = EXP2_SCALE * ||row_i||^2 for
//   i<1024: test rows, i in [1024,5120): train rows.  (needs 20 KB of d_ws)
// main kernel: 2048 blocks = 32 test-blocks(32 tests) x 64 row-slices(64 rows).
//   wave w of a block owns octet = tb*4+w (8 tests, broadcast loads),
//   lane = one train row (float4 stream). 8 indep fma chains, no LDS/syncs.
//   Butterfly-reduce 8 sums over 64 lanes, lane0 atomicAdds.

#define D          64
#define N_TRAIN    4096
#define N_TEST     1024
#define EXP2_SCALE (-450.84220027780106f)   // -log2(e)/0.0032
#define NEG2SCALE  (901.6844005556021f)     // -2*EXP2_SCALE
#define COEF       (9.973557010035818f)     // 1/sqrt(2*pi*var)
#define MEAN_SCALE (COEF / 4096.0f)

__global__ __launch_bounds__(256) void kde_prep(
    const float* __restrict__ test,
    const float* __restrict__ train,
    float* __restrict__ out,
    float* __restrict__ ws)
{
    const int i = blockIdx.x * 256 + threadIdx.x;   // 0..5119
    if (i < N_TEST) out[i] = 0.0f;
    if (i >= N_TEST + N_TRAIN) return;
    const float* src = (i < N_TEST) ? (test + (size_t)i * D)
                                    : (train + (size_t)(i - N_TEST) * D);
    const float4* p = (const float4*)src;
    float n0 = 0.f, n1 = 0.f, n2 = 0.f, n3 = 0.f;
    #pragma unroll
    for (int c = 0; c < D / 4; ++c) {
        float4 v = p[c];
        n0 = fmaf(v.x, v.x, n0); n1 = fmaf(v.y, v.y, n1);
        n2 = fmaf(v.z, v.z, n2); n3 = fmaf(v.w, v.w, n3);
    }
    ws[i] = ((n0 + n1) + (n2 + n3)) * EXP2_SCALE;
}

__global__ __launch_bounds__(256) void kde_main(
    const float* __restrict__ test,
    const float* __restrict__ train,
    const float* __restrict__ ws,
    float* __restrict__ out)
{
    const int lane  = threadIdx.x & 63;
    const int wv    = __builtin_amdgcn_readfirstlane(threadIdx.x >> 6);
    const int tb    = blockIdx.x & 31;     // test-block: 32 tests
    const int slice = blockIdx.x >> 5;     // row-slice: 64 rows, 0..63
    const int t0    = (tb * 4 + wv) * 8;   // this wave's 8 tests
    const int row   = slice * 64 + lane;   // this lane's train row

    const float4* __restrict__ tr = (const float4*)(train + (size_t)row * D);
    const float4* __restrict__ xs = (const float4*)(test + (size_t)t0 * D);

    float acc[8];
    #pragma unroll
    for (int t = 0; t < 8; ++t) acc[t] = 0.0f;

    #pragma unroll 4
    for (int c = 0; c < D / 4; ++c) {
        float4 tv = tr[c];
        #pragma unroll
        for (int t = 0; t < 8; ++t) {
            float4 xv = xs[t * (D / 4) + c];   // wave-uniform -> broadcast
            acc[t] = fmaf(xv.x, tv.x, acc[t]);
            acc[t] = fmaf(xv.y, tv.y, acc[t]);
            acc[t] = fmaf(xv.z, tv.z, acc[t]);
            acc[t] = fmaf(xv.w, tv.w, acc[t]);
        }
    }

    const float rn = ws[N_TEST + row];         // EXP2_SCALE*||row||^2 (per lane)
    float e[8];
    #pragma unroll
    for (int t = 0; t < 8; ++t) {
        const float xn = ws[t0 + t];           // EXP2_SCALE*||x_t||^2 (uniform)
        e[t] = exp2f(fmaf(acc[t], NEG2SCALE, xn + rn));
    }

    // sum each e[t] across the 64 lanes (rows of this slice)
    #pragma unroll
    for (int off = 32; off > 0; off >>= 1) {
        #pragma unroll
        for (int t = 0; t < 8; ++t)
            e[t] += __shfl_xor(e[t], off, 64);
    }

    if (lane == 0) {
        #pragma unroll
        for (int t = 0; t < 8; ++t)
            atomicAdd(&out[t0 + t], e[t] * MEAN_SCALE);
    }
}

extern "C" void kernel_launch(void* const* d_in, const int* in_sizes, int n_in,
                              void* d_out, int out_size, void* d_ws, size_t ws_size,
                              hipStream_t stream) {
    const float* test  = (const float*)d_in[0];   // [4,256,64]
    const float* train = (const float*)d_in[1];   // [4096,64]
    float* out = (float*)d_out;                   // 1024 floats
    float* ws  = (float*)d_ws;                    // 5120 floats used

    kde_prep<<<dim3((N_TEST + N_TRAIN) / 256), dim3(256), 0, stream>>>(test, train, out, ws);
    kde_main<<<dim3(2048), dim3(256), 0, stream>>>(test, train, ws, out);
}

// Round 3
// 92.143 us; speedup vs baseline: 1.2365x; 1.0445x over previous
//
#include <hip/hip_runtime.h>
#include <math.h>

// KDE via dot-product form: sqd = ||x||^2 + ||t||^2 - 2 x.t
// exp(-sqd/(2*var)) = exp2(EXP2_SCALE * sqd), var = 0.04^2, 2var = 0.0032
//
// R3 change: coalesce the train stream. kde_prep repacks train into d_ws as
//   packed[slice][c][lane] (float4 units), slice=row/64, c=dim-chunk 0..15,
//   lane=row%64 -> in kde_main consecutive lanes read consecutive float4s
//   (one 1 KB segment per load instr instead of 64 scattered lines).
// ws layout (floats): [0,5120)   = EXP2_SCALE*||row||^2 (test rows then train)
//                     [8192,...) = packed train, 256K floats (1 MB)

#define D          64
#define N_TRAIN    4096
#define N_TEST     1024
#define PACK_OFF   8192
#define EXP2_SCALE (-450.84220027780106f)   // -log2(e)/0.0032
#define NEG2SCALE  (901.6844005556021f)     // -2*EXP2_SCALE
#define COEF       (9.973557010035818f)     // 1/sqrt(2*pi*var)
#define MEAN_SCALE (COEF / 4096.0f)

__global__ __launch_bounds__(256) void kde_prep(
    const float* __restrict__ test,
    const float* __restrict__ train,
    float* __restrict__ out,
    float* __restrict__ ws)
{
    const int j = blockIdx.x * 256 + threadIdx.x;   // 0..65535

    // Task A: repack train. j indexes float4 units of the packed layout.
    {
        const int slice = j >> 10;          // 1024 float4 per slice
        const int rem   = j & 1023;
        const int c     = rem >> 6;         // dim chunk
        const int lane  = rem & 63;         // row within slice
        const int row   = slice * 64 + lane;
        float4 v = ((const float4*)(train + (size_t)row * D))[c];
        ((float4*)(ws + PACK_OFF))[j] = v;
    }

    // Task B: zero the output.
    if (j < N_TEST) out[j] = 0.0f;

    // Task C: scaled squared norms for test (0..1023) and train (1024..5119).
    if (j < N_TEST + N_TRAIN) {
        const float* src = (j < N_TEST) ? (test + (size_t)j * D)
                                        : (train + (size_t)(j - N_TEST) * D);
        const float4* p = (const float4*)src;
        float n0 = 0.f, n1 = 0.f, n2 = 0.f, n3 = 0.f;
        #pragma unroll
        for (int c = 0; c < D / 4; ++c) {
            float4 v = p[c];
            n0 = fmaf(v.x, v.x, n0); n1 = fmaf(v.y, v.y, n1);
            n2 = fmaf(v.z, v.z, n2); n3 = fmaf(v.w, v.w, n3);
        }
        ws[j] = ((n0 + n1) + (n2 + n3)) * EXP2_SCALE;
    }
}

__global__ __launch_bounds__(256) void kde_main(
    const float* __restrict__ test,
    const float* __restrict__ ws,
    float* __restrict__ out)
{
    const int lane  = threadIdx.x & 63;
    const int wv    = __builtin_amdgcn_readfirstlane(threadIdx.x >> 6);
    const int tb    = blockIdx.x & 31;     // test-block: 32 tests
    const int slice = blockIdx.x >> 5;     // row-slice: 64 rows, 0..63
    const int t0    = (tb * 4 + wv) * 8;   // this wave's 8 tests
    const int row   = slice * 64 + lane;   // this lane's train row

    // packed[slice][c][lane] float4s: consecutive lanes -> consecutive 16 B
    const float4* __restrict__ tr = (const float4*)(ws + PACK_OFF)
                                    + (size_t)slice * 1024 + lane;
    const float4* __restrict__ xs = (const float4*)(test + (size_t)t0 * D);

    float acc[8];
    #pragma unroll
    for (int t = 0; t < 8; ++t) acc[t] = 0.0f;

    #pragma unroll 4
    for (int c = 0; c < D / 4; ++c) {
        float4 tv = tr[c * 64];
        #pragma unroll
        for (int t = 0; t < 8; ++t) {
            float4 xv = xs[t * (D / 4) + c];   // wave-uniform -> sgpr broadcast
            acc[t] = fmaf(xv.x, tv.x, acc[t]);
            acc[t] = fmaf(xv.y, tv.y, acc[t]);
            acc[t] = fmaf(xv.z, tv.z, acc[t]);
            acc[t] = fmaf(xv.w, tv.w, acc[t]);
        }
    }

    const float rn = ws[N_TEST + row];         // EXP2_SCALE*||row||^2 (per lane)
    float e[8];
    #pragma unroll
    for (int t = 0; t < 8; ++t) {
        const float xn = ws[t0 + t];           // EXP2_SCALE*||x_t||^2 (uniform)
        e[t] = exp2f(fmaf(acc[t], NEG2SCALE, xn + rn));
    }

    // sum each e[t] across the 64 lanes (rows of this slice)
    #pragma unroll
    for (int off = 32; off > 0; off >>= 1) {
        #pragma unroll
        for (int t = 0; t < 8; ++t)
            e[t] += __shfl_xor(e[t], off, 64);
    }

    if (lane == 0) {
        #pragma unroll
        for (int t = 0; t < 8; ++t)
            atomicAdd(&out[t0 + t], e[t] * MEAN_SCALE);
    }
}

extern "C" void kernel_launch(void* const* d_in, const int* in_sizes, int n_in,
                              void* d_out, int out_size, void* d_ws, size_t ws_size,
                              hipStream_t stream) {
    const float* test  = (const float*)d_in[0];   // [4,256,64]
    const float* train = (const float*)d_in[1];   // [4096,64]
    float* out = (float*)d_out;                   // 1024 floats
    float* ws  = (float*)d_ws;

    kde_prep<<<dim3(256), dim3(256), 0, stream>>>(test, train, out, ws);
    kde_main<<<dim3(2048), dim3(256), 0, stream>>>(test, ws, out);
}

// Round 4
// 73.617 us; speedup vs baseline: 1.5477x; 1.2517x over previous
//
#include <hip/hip_runtime.h>
#include <math.h>

// KDE, dot-product form: sqd = ||x||^2 + ||t||^2 - 2 x.t
// exp(-sqd/(2*var)) = exp2(EXP2_SCALE*sqd), var=0.04^2, 2var=0.0032
//
// R4: lane = test point. Each lane keeps its 64-dim test vector in VGPRs
// (loaded once from a transposed copy, coalesced). Train rows are wave-uniform
// -> scalarized s_load through K$. Inner loop = pure VALU (64 fma + exp2 per
// row), no VMEM, no shuffles. One coalesced atomicAdd per wave at the end.
//
// ws layout (floats): [0,1024)    EXP2_SCALE*||test_i||^2
//                     [1024,5120) EXP2_SCALE*||train_j||^2
//                     [8192,+64K) testT[k][i] = test[i][k]  (256 KB)

#define D          64
#define N_TRAIN    4096
#define N_TEST     1024
#define TT_OFF     8192
#define ROWS       16                       // train rows per chunk
#define CHUNKS     (N_TRAIN / ROWS)         // 256
#define EXP2_SCALE (-450.84220027780106f)   // -log2(e)/0.0032
#define NEG2SCALE  (901.6844005556021f)     // -2*EXP2_SCALE
#define COEF       (9.973557010035818f)     // 1/sqrt(2*pi*var)
#define MEAN_SCALE (COEF / 4096.0f)

__global__ __launch_bounds__(256) void kde_prep(
    const float* __restrict__ test,
    const float* __restrict__ train,
    float* __restrict__ out,
    float* __restrict__ ws)
{
    const int j = blockIdx.x * 256 + threadIdx.x;   // 0..65535

    // Transpose test -> testT[k][i] (scattered read, coalesced write).
    {
        const int k = j >> 10;
        const int i = j & 1023;
        ws[TT_OFF + j] = test[(size_t)i * D + k];
    }

    if (j < N_TEST) out[j] = 0.0f;

    // Scaled squared norms: test rows then train rows.
    if (j < N_TEST + N_TRAIN) {
        const float* src = (j < N_TEST) ? (test + (size_t)j * D)
                                        : (train + (size_t)(j - N_TEST) * D);
        const float4* p = (const float4*)src;
        float n0 = 0.f, n1 = 0.f, n2 = 0.f, n3 = 0.f;
        #pragma unroll
        for (int c = 0; c < D / 4; ++c) {
            float4 v = p[c];
            n0 = fmaf(v.x, v.x, n0); n1 = fmaf(v.y, v.y, n1);
            n2 = fmaf(v.z, v.z, n2); n3 = fmaf(v.w, v.w, n3);
        }
        ws[j] = ((n0 + n1) + (n2 + n3)) * EXP2_SCALE;
    }
}

__global__ __launch_bounds__(256) void kde_main(
    const float* __restrict__ train,
    const float* __restrict__ ws,
    float* __restrict__ out)
{
    const int lane  = threadIdx.x & 63;
    const int wv    = threadIdx.x >> 6;
    const int tg    = blockIdx.x & 3;      // test group (256 tests)
    const int chunk = blockIdx.x >> 2;     // train row chunk (16 rows)
    const int ti    = tg * 256 + wv * 64 + lane;   // this lane's test point

    // One-time: pull this lane's test vector into VGPRs (coalesced dword loads).
    const float* __restrict__ tt = ws + TT_OFF + ti;
    float x[D];
    #pragma unroll
    for (int k = 0; k < D; ++k) x[k] = tt[(size_t)k * 1024];
    const float xn = ws[ti];                       // per-lane scaled ||x||^2

    float sum = 0.0f;
    const int j0 = chunk * ROWS;
    for (int jj = 0; jj < ROWS; ++jj) {
        const int j = j0 + jj;                     // wave-uniform row index
        const float* __restrict__ trow = train + (size_t)j * D;
        float d0 = 0.f, d1 = 0.f, d2 = 0.f, d3 = 0.f;
        #pragma unroll
        for (int k = 0; k < D; k += 4) {
            d0 = fmaf(trow[k + 0], x[k + 0], d0);  // trow[k]: uniform -> sgpr
            d1 = fmaf(trow[k + 1], x[k + 1], d1);
            d2 = fmaf(trow[k + 2], x[k + 2], d2);
            d3 = fmaf(trow[k + 3], x[k + 3], d3);
        }
        const float tn  = ws[N_TEST + j];          // uniform scaled ||t||^2
        const float dot = (d0 + d1) + (d2 + d3);
        sum += exp2f(fmaf(dot, NEG2SCALE, xn + tn));
    }

    atomicAdd(&out[ti], sum * MEAN_SCALE);         // coalesced, per-lane
}

extern "C" void kernel_launch(void* const* d_in, const int* in_sizes, int n_in,
                              void* d_out, int out_size, void* d_ws, size_t ws_size,
                              hipStream_t stream) {
    const float* test  = (const float*)d_in[0];   // [4,256,64]
    const float* train = (const float*)d_in[1];   // [4096,64]
    float* out = (float*)d_out;                   // 1024 floats
    float* ws  = (float*)d_ws;

    kde_prep<<<dim3(256), dim3(256), 0, stream>>>(test, train, out, ws);
    kde_main<<<dim3(4 * CHUNKS), dim3(256), 0, stream>>>(train, ws, out);
}